// Round 9
// baseline (11618.269 us; speedup 1.0000x reference)
//
#include <hip/hip_runtime.h>
#include <cmath>

// DGCNN: B=8, N=2048, k=20, dims 3->64->128->256, fp32 throughout.
static constexpr int Bb  = 8;
static constexpr int Nn  = 2048;
static constexpr int KNB = 20;
static constexpr int NPT = Bb * Nn;
#define EPSBN 1e-5f

// LDS column swizzle used by gemmAB (b128 reads over 128-col tiles).
__device__ __forceinline__ int permc(int c) { return c ^ (4 * (c >> 5)); }

// ---------------------------------------------------------------- row |x|^2
__global__ __launch_bounds__(256) void row_sumsq_k(const float* __restrict__ f,
                                                   float* __restrict__ xx, int C) {
  int g = blockIdx.x * 256 + threadIdx.x;
  if (g >= NPT) return;
  const float* r = f + (size_t)g * C;
  float s = 0.f;
  for (int j = 0; j < C; ++j) { float v = r[j]; s += v * v; }
  xx[g] = s;
}

// ------------------------------------------------- exact lex top-20 selection
// Selection-sort the top KNB of m entries into the head, ordered by
// (key desc, index asc) — matches lax.top_k tie-breaking. Serial, one thread.
__device__ __forceinline__ void sel20(unsigned* ck, unsigned short* ci, int m) {
  for (int p = 0; p < KNB; ++p) {
    unsigned bk = ck[p]; unsigned short bi = ci[p]; int best = p;
    for (int j = p + 1; j < m; ++j) {
      unsigned kj = ck[j]; unsigned short ij = ci[j];
      if (kj > bk || (kj == bk && ij < bi)) { bk = kj; bi = ij; best = j; }
    }
    ck[best] = ck[p]; ci[best] = ci[p];
    ck[p] = bk; ci[p] = bi;
  }
}

// ------------------------------------------------- fused kNN: dist + top-20
// One block per (batch, 32-row strip): 512 blocks. nd is NEVER materialized.
// A-strip LDS-resident K-major; stream 64-col tiles with 16-K panels.
// Streaming exact top-20 per row: threshold-append (key >= T) into CAP=128
// LDS buffer; compact to exact top-20 when cnt > 64 (tile adds <= 64 so the
// buffer can never overflow). Tile-0 threshold seeded conservatively with
// min-over-lanes(lane 2nd-largest): >=32 keys >= seed, so nothing in the true
// top-20 is ever rejected. Keys are the standard monotone uint map of f32.
// LESSONS (R6/R7): no launch_bounds min-waves (spill), no runtime-indexed
// register arrays (demotes to scratch) — all acc/ukey indices unroll-constant.
template <int C, int KP>
__global__ __launch_bounds__(256) void knn_k(const float* __restrict__ f,
                                             const float* __restrict__ xx,
                                             int* __restrict__ outidx) {
  constexpr int CAP = 128, SK = 129, SI = 130;   // odd strides: no 32-lane bank alias
  __shared__ float As[KP * 34];                  // [k][row] rows 0..31 (+2 pad)
  __shared__ float Bs[16 * 68];                  // [k][col] cols 0..63
  __shared__ float xs[Nn];                       // batch |x|^2
  __shared__ unsigned ckA[32 * SK];              // candidate keys per row
  __shared__ unsigned short ciA[32 * SI];        // candidate col indices
  __shared__ int cnt[32];
  __shared__ unsigned Tt[32];
  int tid = threadIdx.x, tx = tid & 15, ty = tid >> 4;
  int batch = blockIdx.x & 7, strip = blockIdx.x >> 3;   // batch==XCD for L2 locality
  int rb = strip * 32;
  const float* fb  = f  + (size_t)batch * Nn * C;
  const float* xxb = xx + (size_t)batch * Nn;
  for (int i = tid; i < Nn; i += 256) xs[i] = xxb[i];
  for (int idx = tid; idx < 32 * KP; idx += 256) {
    int k = idx % KP, row = idx / KP;
    As[k * 34 + row] = (k < C) ? fb[(size_t)(rb + row) * C + k] : 0.f;
  }
  if (tid < 32) { cnt[tid] = 0; Tt[tid] = 0u; }
  __syncthreads();
  float xr0 = xs[rb + 2 * ty], xr1 = xs[rb + 2 * ty + 1];
  for (int tile = 0; tile < Nn / 64; ++tile) {
    int cb = tile * 64;
    float acc[2][4] = {};
    for (int k0 = 0; k0 < KP; k0 += 16) {
      __syncthreads();
      for (int t = tid; t < 1024; t += 256) {
        int col = t >> 4, k = t & 15, kg = k0 + k;
        Bs[k * 68 + col] = (kg < C) ? fb[(size_t)(cb + col) * C + kg] : 0.f;
      }
      __syncthreads();
      #pragma unroll
      for (int kk = 0; kk < 16; ++kk) {
        float2 a2 = *(const float2*)&As[(k0 + kk) * 34 + 2 * ty];
        float4 b4 = *(const float4*)&Bs[kk * 68 + 4 * tx];
        float bv[4] = {b4.x, b4.y, b4.z, b4.w};
        #pragma unroll
        for (int j = 0; j < 4; ++j) {
          acc[0][j] += a2.x * bv[j];
          acc[1][j] += a2.y * bv[j];
        }
      }
    }
    // finalize distances -> monotone keys
    float xc[4];
    #pragma unroll
    for (int j = 0; j < 4; ++j) xc[j] = xs[cb + 4 * tx + j];
    unsigned ukey[2][4];
    #pragma unroll
    for (int i = 0; i < 2; ++i) {
      int grow = rb + 2 * ty + i;
      float xri = (i == 0) ? xr0 : xr1;
      #pragma unroll
      for (int j = 0; j < 4; ++j) {
        int col = cb + 4 * tx + j;
        float v = 2.f * acc[i][j] - xri - xc[j];
        if (grow == col) v = 0.f;                 // diag exactly 0 (as reference)
        unsigned u = __float_as_uint(v);
        ukey[i][j] = (u & 0x80000000u) ? ~u : (u | 0x80000000u);
      }
    }
    unsigned thr0, thr1;
    if (tile == 0) {
      // conservative seed: min over 16 lanes of lane-2nd-largest
      unsigned m2a, m2b;
      #pragma unroll
      for (int i = 0; i < 2; ++i) {
        unsigned k1 = 0, k2 = 0;
        #pragma unroll
        for (int j = 0; j < 4; ++j) {
          unsigned kj = ukey[i][j];
          if (kj > k1) { k2 = k1; k1 = kj; }
          else if (kj > k2) k2 = kj;
        }
        unsigned m2 = k2;
        #pragma unroll
        for (int off = 1; off < 16; off <<= 1) {
          unsigned o = (unsigned)__shfl_xor((int)m2, off, 64);
          m2 = (o < m2) ? o : m2;
        }
        if (i == 0) m2a = m2; else m2b = m2;
      }
      thr0 = m2a; thr1 = m2b;
      if (tx == 0) { Tt[2 * ty] = thr0; Tt[2 * ty + 1] = thr1; }
    } else {
      thr0 = Tt[2 * ty]; thr1 = Tt[2 * ty + 1];
    }
    #pragma unroll
    for (int i = 0; i < 2; ++i) {
      int r = 2 * ty + i;
      unsigned thr = (i == 0) ? thr0 : thr1;
      #pragma unroll
      for (int j = 0; j < 4; ++j) {
        if (ukey[i][j] >= thr) {
          int pos = atomicAdd(&cnt[r], 1);
          if (pos < CAP) {
            ckA[r * SK + pos] = ukey[i][j];
            ciA[r * SI + pos] = (unsigned short)(cb + 4 * tx + j);
          }
        }
      }
    }
    __syncthreads();
    if (tile != Nn / 64 - 1 && tid < 32 && cnt[tid] > 64) {
      sel20(&ckA[tid * SK], &ciA[tid * SI], cnt[tid] < CAP ? cnt[tid] : CAP);
      cnt[tid] = KNB;
      Tt[tid] = ckA[tid * SK + KNB - 1];          // exact 20th-largest so far
    }
    // next tile's staging barrier orders compaction vs appends
  }
  __syncthreads();
  if (tid < 32) {
    int m = cnt[tid] < CAP ? cnt[tid] : CAP;
    sel20(&ckA[tid * SK], &ciA[tid * SI], m);
    size_t grow = (size_t)batch * Nn + rb + tid;
    for (int q = 0; q < KNB; ++q)
      outidx[grow * KNB + q] = (int)ciA[tid * SI + q];
  }
}

// ------------------------------------------------- fused GEMM: A = X*W1^T + b, Bv = X*W2^T
__global__ __launch_bounds__(256) void gemmAB_k(const float* __restrict__ X,
                                                const float* __restrict__ W,
                                                const float* __restrict__ bias,
                                                float* __restrict__ A,
                                                float* __restrict__ Bv,
                                                int COUT, int CIN) {
  __shared__ float Xs[16][132];
  __shared__ float Ws[16][132];
  int tid = threadIdx.x, tx = tid & 15, ty = tid >> 4;
  int mb = blockIdx.y * 128, cb = blockIdx.x * 128;
  int kk0 = tid & 15, rr = tid >> 4;
  int ldw = 2 * CIN;
  float acc[8][8] = {};
  for (int k0 = 0; k0 < CIN; k0 += 16) {
    int k = k0 + kk0;
    bool ok = k < CIN;
    #pragma unroll
    for (int r2 = rr; r2 < 128; r2 += 16) {
      Xs[kk0][permc(r2)] = ok ? X[(size_t)(mb + r2) * CIN + k] : 0.f;
      int c2 = cb + r2;
      const float* wr = (c2 < COUT) ? (W + (size_t)c2 * ldw)
                                    : (W + (size_t)(c2 - COUT) * ldw + CIN);
      Ws[kk0][permc(r2)] = ok ? wr[k] : 0.f;
    }
    __syncthreads();
    #pragma unroll
    for (int kk = 0; kk < 16; ++kk) {
      float4 a0 = *(const float4*)&Xs[kk][permc(8 * ty)];
      float4 a1 = *(const float4*)&Xs[kk][permc(8 * ty + 4)];
      float4 b0 = *(const float4*)&Ws[kk][permc(8 * tx)];
      float4 b1 = *(const float4*)&Ws[kk][permc(8 * tx + 4)];
      float av[8] = {a0.x, a0.y, a0.z, a0.w, a1.x, a1.y, a1.z, a1.w};
      float bv[8] = {b0.x, b0.y, b0.z, b0.w, b1.x, b1.y, b1.z, b1.w};
      #pragma unroll
      for (int i = 0; i < 8; ++i)
        #pragma unroll
        for (int j = 0; j < 8; ++j) acc[i][j] += av[i] * bv[j];
    }
    __syncthreads();
  }
  int c0 = cb + 8 * tx;
  bool isA = (c0 < COUT);
  float bb[8] = {0, 0, 0, 0, 0, 0, 0, 0};
  if (isA) {
    float4 b4a = *(const float4*)&bias[c0];
    float4 b4b = *(const float4*)&bias[c0 + 4];
    bb[0] = b4a.x; bb[1] = b4a.y; bb[2] = b4a.z; bb[3] = b4a.w;
    bb[4] = b4b.x; bb[5] = b4b.y; bb[6] = b4b.z; bb[7] = b4b.w;
  }
  float* dst = isA ? A : Bv;
  int cc = isA ? c0 : (c0 - COUT);
  #pragma unroll
  for (int i = 0; i < 8; ++i) {
    int m = mb + 8 * ty + i;
    *(float4*)&dst[(size_t)m * COUT + cc] =
        make_float4(acc[i][0] + bb[0], acc[i][1] + bb[1], acc[i][2] + bb[2], acc[i][3] + bb[3]);
    *(float4*)&dst[(size_t)m * COUT + cc + 4] =
        make_float4(acc[i][4] + bb[4], acc[i][5] + bb[5], acc[i][6] + bb[6], acc[i][7] + bb[7]);
  }
}

// ------------------------------------------------- gather-combine + stats
// XCD-aware: batch = blockIdx.x % 8 so each XCD's L2 caches one batch's Bv slice.
template <int COUT>
__global__ __launch_bounds__(256) void combine_k(const float* __restrict__ A,
                                                 const float* __restrict__ Bv,
                                                 const int* __restrict__ idx,
                                                 float* __restrict__ maxh,
                                                 float* __restrict__ minh,
                                                 float* __restrict__ gsum,
                                                 float* __restrict__ gsumsq) {
  constexpr int TPP = COUT / 4;
  constexpr int P = 256 / TPP;
  constexpr int PTS = 16;
  __shared__ float red[8][256];
  int tid = threadIdx.x;
  int p = tid / TPP, cq = tid % TPP;
  int b = blockIdx.x & 7, chunk = blockIdx.x >> 3;
  int nbase = b * Nn + chunk * PTS;
  const float4* A4 = (const float4*)A;
  const float4* B4 = (const float4*)Bv;
  float4 ts = make_float4(0, 0, 0, 0), ts2 = make_float4(0, 0, 0, 0);
  for (int it = 0; it < PTS / P; ++it) {
    int n = nbase + it * P + p;
    float4 a  = A4[(size_t)n * TPP + cq];
    float4 bc = B4[(size_t)n * TPP + cq];
    float4 base = make_float4(a.x - bc.x, a.y - bc.y, a.z - bc.z, a.w - bc.w);
    float4 mx = make_float4(-INFINITY, -INFINITY, -INFINITY, -INFINITY);
    float4 mn = make_float4(INFINITY, INFINITY, INFINITY, INFINITY);
    int gb = b * Nn;
    const int* ip = idx + (size_t)n * KNB;
    for (int k = 0; k < KNB; ++k) {
      int m = ip[k];
      float4 bn = B4[(size_t)(gb + m) * TPP + cq];
      float4 h = make_float4(base.x + bn.x, base.y + bn.y, base.z + bn.z, base.w + bn.w);
      mx.x = fmaxf(mx.x, h.x); mx.y = fmaxf(mx.y, h.y);
      mx.z = fmaxf(mx.z, h.z); mx.w = fmaxf(mx.w, h.w);
      mn.x = fminf(mn.x, h.x); mn.y = fminf(mn.y, h.y);
      mn.z = fminf(mn.z, h.z); mn.w = fminf(mn.w, h.w);
      ts.x += h.x; ts.y += h.y; ts.z += h.z; ts.w += h.w;
      ts2.x += h.x * h.x; ts2.y += h.y * h.y; ts2.z += h.z * h.z; ts2.w += h.w * h.w;
    }
    ((float4*)maxh)[(size_t)n * TPP + cq] = mx;
    ((float4*)minh)[(size_t)n * TPP + cq] = mn;
  }
  red[0][tid] = ts.x;  red[1][tid] = ts.y;  red[2][tid] = ts.z;  red[3][tid] = ts.w;
  red[4][tid] = ts2.x; red[5][tid] = ts2.y; red[6][tid] = ts2.z; red[7][tid] = ts2.w;
  __syncthreads();
  if (tid < COUT) {
    int q = tid & 3, g = tid >> 2;
    float s = 0.f, s2 = 0.f;
    for (int pp = 0; pp < P; ++pp) {
      int t2 = pp * TPP + g;
      s += red[q][t2]; s2 += red[4 + q][t2];
    }
    atomicAdd(&gsum[tid], s);
    atomicAdd(&gsumsq[tid], s2);
  }
}

// ------------------------------------------------- BN scale/shift per channel
__global__ void stats_k(const float* __restrict__ gsum, const float* __restrict__ gsumsq,
                        const float* __restrict__ gamma, const float* __restrict__ beta,
                        float* __restrict__ sA, float* __restrict__ sB, int COUT) {
  int c = threadIdx.x;
  if (c < COUT) {
    const float cnt = (float)((size_t)Bb * Nn * KNB);
    float mean = gsum[c] / cnt;
    float var = gsumsq[c] / cnt - mean * mean;
    var = fmaxf(var, 0.f);
    float s = gamma[c] * rsqrtf(var + EPSBN);
    sA[c] = s;
    sB[c] = beta[c] - mean * s;
  }
}

// ------------------------------------------------- apply BN+ReLU
__global__ __launch_bounds__(256) void apply_k(const float* __restrict__ maxh,
                                               const float* __restrict__ minh,
                                               const float* __restrict__ sA,
                                               const float* __restrict__ sB,
                                               float* __restrict__ out, int COUT) {
  int i = blockIdx.x * 256 + threadIdx.x;
  if (i >= NPT * COUT) return;
  int c = i % COUT;
  float s = sA[c];
  float h = (s >= 0.f) ? maxh[i] : minh[i];
  out[i] = fmaxf(s * h + sB[c], 0.f);
}

// ------------------------------------------------- global max pool over N
__global__ __launch_bounds__(256) void gmax_k(const float* __restrict__ feat,
                                              unsigned* __restrict__ pooled) {
  int b = blockIdx.y, chunk = blockIdx.x;
  int c = threadIdx.x;
  const float* fb = feat + ((size_t)b * Nn + chunk * 32) * 256;
  float m = 0.f;
  #pragma unroll 8
  for (int r = 0; r < 32; ++r) m = fmaxf(m, fb[(size_t)r * 256 + c]);
  atomicMax(&pooled[b * 256 + c], __float_as_uint(m));
}

// ------------------------------------------------- final linear 8x256 @ 256x256
__global__ void final_k(const float* __restrict__ pooled, const float* __restrict__ wo,
                        const float* __restrict__ bo, float* __restrict__ out) {
  int b = blockIdx.x, c = threadIdx.x;
  const float* pr = pooled + b * 256;
  const float* wr = wo + c * 256;
  float s = bo[c];
  for (int j = 0; j < 256; ++j) s += pr[j] * wr[j];
  out[b * 256 + c] = s;
}

// ------------------------------------------------- layer driver
template <int CIN, int COUT>
static void run_layer(const float* fin, const float* W, const float* bias,
                      const float* gamma, const float* beta, float* fout,
                      float* Abuf, float* Bvbuf, int* idxb, float* xx,
                      float* maxh, float* minh, float* gsum,
                      float* sA, float* sB, hipStream_t stream) {
  constexpr int KP = ((CIN + 15) / 16) * 16;
  row_sumsq_k<<<(NPT + 255) / 256, 256, 0, stream>>>(fin, xx, CIN);
  knn_k<CIN, KP><<<512, 256, 0, stream>>>(fin, xx, idxb);
  gemmAB_k<<<dim3(2 * COUT / 128, NPT / 128), 256, 0, stream>>>(fin, W, bias,
                                                                Abuf, Bvbuf, COUT, CIN);
  hipMemsetAsync(gsum, 0, 2 * 256 * sizeof(float), stream);
  combine_k<COUT><<<NPT / 16, 256, 0, stream>>>(Abuf, Bvbuf, idxb, maxh, minh,
                                                gsum, gsum + 256);
  stats_k<<<1, 256, 0, stream>>>(gsum, gsum + 256, gamma, beta, sA, sB, COUT);
  apply_k<<<(NPT * COUT + 255) / 256, 256, 0, stream>>>(maxh, minh, sA, sB, fout, COUT);
}

extern "C" void kernel_launch(void* const* d_in, const int* in_sizes, int n_in,
                              void* d_out, int out_size, void* d_ws, size_t ws_size,
                              hipStream_t stream) {
  const float* x   = (const float*)d_in[0];
  const float* w1  = (const float*)d_in[1];
  const float* b1  = (const float*)d_in[2];
  const float* g1  = (const float*)d_in[3];
  const float* be1 = (const float*)d_in[4];
  const float* w2  = (const float*)d_in[5];
  const float* b2  = (const float*)d_in[6];
  const float* g2  = (const float*)d_in[7];
  const float* be2 = (const float*)d_in[8];
  const float* w3  = (const float*)d_in[9];
  const float* b3  = (const float*)d_in[10];
  const float* g3  = (const float*)d_in[11];
  const float* be3 = (const float*)d_in[12];
  const float* wo  = (const float*)d_in[13];
  const float* bo  = (const float*)d_in[14];
  float* out = (float*)d_out;

  // Workspace ~81 MB (no nd matrix anymore — kNN is fused).
  char* ws = (char*)d_ws;
  size_t off = 0;
  auto grab = [&](size_t bytes) -> char* {
    char* p = ws + off;
    off = (off + bytes + 255) & ~(size_t)255;
    return p;
  };
  const size_t SLAB = (size_t)NPT * 256 * 4;          // 16.78 MB
  float* Abuf  = (float*)grab(SLAB);
  float* Bvbuf = (float*)grab(SLAB);
  int*   idxb  = (int*)  grab((size_t)NPT * KNB * 4);
  float* xx    = (float*)grab((size_t)NPT * 4);
  float* feat1 = (float*)grab((size_t)NPT * 64 * 4);
  float* feat2 = (float*)grab((size_t)NPT * 128 * 4);
  float* maxh  = (float*)grab(SLAB);
  float* minh  = (float*)grab(SLAB);
  float* feat3 = minh;   // apply reads minh[i] then writes feat3[i]: safe alias
  float* gsum  = (float*)grab(2 * 256 * 4);
  float* sA    = (float*)grab(256 * 4);
  float* sB    = (float*)grab(256 * 4);
  unsigned* pooled = (unsigned*)grab(Bb * 256 * 4);

  run_layer<3, 64>(x, w1, b1, g1, be1, feat1, Abuf, Bvbuf, idxb, xx,
                   maxh, minh, gsum, sA, sB, stream);
  run_layer<64, 128>(feat1, w2, b2, g2, be2, feat2, Abuf, Bvbuf, idxb, xx,
                     maxh, minh, gsum, sA, sB, stream);
  run_layer<128, 256>(feat2, w3, b3, g3, be3, feat3, Abuf, Bvbuf, idxb, xx,
                      maxh, minh, gsum, sA, sB, stream);

  hipMemsetAsync(pooled, 0, Bb * 256 * sizeof(unsigned), stream);
  gmax_k<<<dim3(Nn / 32, Bb), 256, 0, stream>>>(feat3, pooled);
  final_k<<<Bb, 256, 0, stream>>>((const float*)pooled, wo, bo, out);
  (void)in_sizes; (void)n_in; (void)out_size; (void)ws_size;
}

// Round 10
// 3447.915 us; speedup vs baseline: 3.3697x; 3.3697x over previous
//
#include <hip/hip_runtime.h>
#include <cmath>

// DGCNN: B=8, N=2048, k=20, dims 3->64->128->256, fp32 throughout.
static constexpr int Bb  = 8;
static constexpr int Nn  = 2048;
static constexpr int KNB = 20;
static constexpr int NPT = Bb * Nn;
#define EPSBN 1e-5f

// LDS column swizzle used by gemmAB (b128 reads over 128-col tiles).
__device__ __forceinline__ int permc(int c) { return c ^ (4 * (c >> 5)); }

// monotone uint key: order(key) == order(float), all-positive
__device__ __forceinline__ unsigned mkkey(float v) {
  unsigned u = __float_as_uint(v);
  return (u & 0x80000000u) ? ~u : (u | 0x80000000u);
}

// ---------------------------------------------------------------- row |x|^2
__global__ __launch_bounds__(256) void row_sumsq_k(const float* __restrict__ f,
                                                   float* __restrict__ xx, int C) {
  int g = blockIdx.x * 256 + threadIdx.x;
  if (g >= NPT) return;
  const float* r = f + (size_t)g * C;
  float s = 0.f;
  for (int j = 0; j < C; ++j) { float v = r[j]; s += v * v; }
  xx[g] = s;
}

// ---------------------------------------------------- cooperative top-20
// 16 lanes of one row cooperatively move the lex-top-20 (key desc, idx asc —
// matches lax.top_k tie-break) of ck/ci[0..m) into slots [0,20) via swap-based
// extraction. Wave-local: no barriers. ~20*(m/16 + 4 shuffles) steps.
__device__ __forceinline__ void compact_row(unsigned* ck, unsigned short* ci,
                                            int m, int tx) {
  for (int q = 0; q < KNB; ++q) {
    unsigned bk = 0; unsigned bi = 0xffffu; int bp = -1;
    for (int j = q + tx; j < m; j += 16) {
      unsigned kj = ck[j]; unsigned ij = ci[j];
      if (kj > bk || (kj == bk && ij < bi)) { bk = kj; bi = ij; bp = j; }
    }
    unsigned wk = bk, wi = bi;
    #pragma unroll
    for (int off = 1; off < 16; off <<= 1) {
      unsigned ok = (unsigned)__shfl_xor((int)wk, off, 64);
      unsigned oi = (unsigned)__shfl_xor((int)wi, off, 64);
      if (ok > wk || (ok == wk && oi < wi)) { wk = ok; wi = oi; }
    }
    if (bp >= 0 && bk == wk && bi == wi) {   // unique winner lane (idx unique)
      unsigned oq = ck[q]; unsigned short oiq = ci[q];
      ck[bp] = oq; ci[bp] = oiq;             // swap old head out
      ck[q] = wk;  ci[q] = (unsigned short)wi;
    }
  }
}

// ------------------------------------------------- fused kNN: dist + top-20
// Block = (batch, 32-row strip); 512 blocks; nd never materialized. A-strip
// LDS K-major; stream 64-col tiles, 16-K panels. Per-row streaming exact
// top-20: running threshold T = max over tiles of wave-min(lane top-2) and,
// after compactions, the exact 20th-so-far. Appends (key >= T) go to a CAP=128
// LDS buffer; compact (cooperative, wave-local) when cnt > 64 — tile adds
// <= 64 so the buffer never overflows. Safety: >=32 keys >= T at all times so
// T <= 20th-so-far <= 20th-final; members of the final top-20 are always
// appended and never evicted (top-20 of any subset containing them).
// LESSONS (R6/R7/R9): no launch_bounds min-waves; no runtime-indexed register
// arrays; NO serial single-lane LDS selection loops (R9: 97% idle).
template <int C, int KP>
__global__ __launch_bounds__(256) void knn_k(const float* __restrict__ f,
                                             const float* __restrict__ xx,
                                             int* __restrict__ outidx) {
  constexpr int CAP = 128, SK = 129, SI = 130;
  __shared__ float As[KP * 34];                  // [k][row], 32 rows (+2 pad)
  __shared__ float Bs[16 * 68];                  // [k][col], 64 cols
  __shared__ unsigned ckA[32 * SK];
  __shared__ unsigned short ciA[32 * SI];
  __shared__ int cnt[32];
  int tid = threadIdx.x, tx = tid & 15, ty = tid >> 4;
  int batch = blockIdx.x & 7, strip = blockIdx.x >> 3;   // batch==XCD slot
  int rb = strip * 32;
  const float* fb  = f  + (size_t)batch * Nn * C;
  const float* xxb = xx + (size_t)batch * Nn;
  for (int idx = tid; idx < 32 * KP; idx += 256) {
    int k = idx % KP, row = idx / KP;
    As[k * 34 + row] = (k < C) ? fb[(size_t)(rb + row) * C + k] : 0.f;
  }
  if (tid < 32) cnt[tid] = 0;
  __syncthreads();
  int r0 = 2 * ty, r1 = 2 * ty + 1;
  unsigned* ck0 = &ckA[r0 * SK]; unsigned short* ci0 = &ciA[r0 * SI];
  unsigned* ck1 = &ckA[r1 * SK]; unsigned short* ci1 = &ciA[r1 * SI];
  float xr0 = xxb[rb + r0], xr1 = xxb[rb + r1];
  unsigned t1a = 0, t2a = 0, t1b = 0, t2b = 0;   // per-lane running top-2
  unsigned T0 = 0, T1 = 0;                        // per-row thresholds
  for (int tile = 0; tile < Nn / 64; ++tile) {
    int cb = tile * 64;
    float acc[2][4] = {};
    for (int k0 = 0; k0 < KP; k0 += 16) {
      __syncthreads();
      for (int t = tid; t < 1024; t += 256) {
        int col = t >> 4, k = t & 15, kg = k0 + k;
        Bs[k * 68 + col] = (kg < C) ? fb[(size_t)(cb + col) * C + kg] : 0.f;
      }
      __syncthreads();
      #pragma unroll
      for (int kk = 0; kk < 16; ++kk) {
        float2 a2 = *(const float2*)&As[(k0 + kk) * 34 + 2 * ty];
        float4 b4 = *(const float4*)&Bs[kk * 68 + 4 * tx];
        acc[0][0] += a2.x * b4.x; acc[0][1] += a2.x * b4.y;
        acc[0][2] += a2.x * b4.z; acc[0][3] += a2.x * b4.w;
        acc[1][0] += a2.y * b4.x; acc[1][1] += a2.y * b4.y;
        acc[1][2] += a2.y * b4.z; acc[1][3] += a2.y * b4.w;
      }
    }
    float4 xc4 = *(const float4*)&xxb[cb + 4 * tx];
    float xc[4] = {xc4.x, xc4.y, xc4.z, xc4.w};
    unsigned ka[4], kb[4];
    #pragma unroll
    for (int j = 0; j < 4; ++j) {
      int col = cb + 4 * tx + j;
      float v0 = 2.f * acc[0][j] - xr0 - xc[j];
      if (rb + r0 == col) v0 = 0.f;               // diag exactly 0 (reference)
      float v1 = 2.f * acc[1][j] - xr1 - xc[j];
      if (rb + r1 == col) v1 = 0.f;
      ka[j] = mkkey(v0); kb[j] = mkkey(v1);
      if (ka[j] > t1a) { t2a = t1a; t1a = ka[j]; } else if (ka[j] > t2a) t2a = ka[j];
      if (kb[j] > t1b) { t2b = t1b; t1b = kb[j]; } else if (kb[j] > t2b) t2b = kb[j];
    }
    unsigned m0 = t2a, m1 = t2b;
    #pragma unroll
    for (int off = 1; off < 16; off <<= 1) {
      unsigned o0 = (unsigned)__shfl_xor((int)m0, off, 64);
      unsigned o1 = (unsigned)__shfl_xor((int)m1, off, 64);
      if (o0 < m0) m0 = o0;
      if (o1 < m1) m1 = o1;
    }
    if (m0 > T0) T0 = m0;
    if (m1 > T1) T1 = m1;
    #pragma unroll
    for (int j = 0; j < 4; ++j) {
      unsigned short col = (unsigned short)(cb + 4 * tx + j);
      if (ka[j] >= T0) {
        int pos = atomicAdd(&cnt[r0], 1);
        if (pos < CAP) { ck0[pos] = ka[j]; ci0[pos] = col; }
      }
      if (kb[j] >= T1) {
        int pos = atomicAdd(&cnt[r1], 1);
        if (pos < CAP) { ck1[pos] = kb[j]; ci1[pos] = col; }
      }
    }
    if (tile != Nn / 64 - 1) {
      int c0 = cnt[r0];
      if (c0 > 64) {
        compact_row(ck0, ci0, c0 < CAP ? c0 : CAP, tx);
        if (tx == 0) cnt[r0] = KNB;
        unsigned nt = ck0[KNB - 1];
        if (nt > T0) T0 = nt;
      }
      int c1 = cnt[r1];
      if (c1 > 64) {
        compact_row(ck1, ci1, c1 < CAP ? c1 : CAP, tx);
        if (tx == 0) cnt[r1] = KNB;
        unsigned nt = ck1[KNB - 1];
        if (nt > T1) T1 = nt;
      }
    }
  }
  // final: exact top-20 per row, cooperative store (order is free downstream)
  {
    int c0 = cnt[r0];
    compact_row(ck0, ci0, c0 < CAP ? c0 : CAP, tx);
    size_t base0 = ((size_t)batch * Nn + rb + r0) * KNB;
    for (int q = tx; q < KNB; q += 16) outidx[base0 + q] = (int)ci0[q];
    int c1 = cnt[r1];
    compact_row(ck1, ci1, c1 < CAP ? c1 : CAP, tx);
    size_t base1 = ((size_t)batch * Nn + rb + r1) * KNB;
    for (int q = tx; q < KNB; q += 16) outidx[base1 + q] = (int)ci1[q];
  }
}

// ------------------------------------------------- fused GEMM: A = X*W1^T + b, Bv = X*W2^T
__global__ __launch_bounds__(256) void gemmAB_k(const float* __restrict__ X,
                                                const float* __restrict__ W,
                                                const float* __restrict__ bias,
                                                float* __restrict__ A,
                                                float* __restrict__ Bv,
                                                int COUT, int CIN) {
  __shared__ float Xs[16][132];
  __shared__ float Ws[16][132];
  int tid = threadIdx.x, tx = tid & 15, ty = tid >> 4;
  int mb = blockIdx.y * 128, cb = blockIdx.x * 128;
  int kk0 = tid & 15, rr = tid >> 4;
  int ldw = 2 * CIN;
  float acc[8][8] = {};
  for (int k0 = 0; k0 < CIN; k0 += 16) {
    int k = k0 + kk0;
    bool ok = k < CIN;
    #pragma unroll
    for (int r2 = rr; r2 < 128; r2 += 16) {
      Xs[kk0][permc(r2)] = ok ? X[(size_t)(mb + r2) * CIN + k] : 0.f;
      int c2 = cb + r2;
      const float* wr = (c2 < COUT) ? (W + (size_t)c2 * ldw)
                                    : (W + (size_t)(c2 - COUT) * ldw + CIN);
      Ws[kk0][permc(r2)] = ok ? wr[k] : 0.f;
    }
    __syncthreads();
    #pragma unroll
    for (int kk = 0; kk < 16; ++kk) {
      float4 a0 = *(const float4*)&Xs[kk][permc(8 * ty)];
      float4 a1 = *(const float4*)&Xs[kk][permc(8 * ty + 4)];
      float4 b0 = *(const float4*)&Ws[kk][permc(8 * tx)];
      float4 b1 = *(const float4*)&Ws[kk][permc(8 * tx + 4)];
      float av[8] = {a0.x, a0.y, a0.z, a0.w, a1.x, a1.y, a1.z, a1.w};
      float bv[8] = {b0.x, b0.y, b0.z, b0.w, b1.x, b1.y, b1.z, b1.w};
      #pragma unroll
      for (int i = 0; i < 8; ++i)
        #pragma unroll
        for (int j = 0; j < 8; ++j) acc[i][j] += av[i] * bv[j];
    }
    __syncthreads();
  }
  int c0 = cb + 8 * tx;
  bool isA = (c0 < COUT);
  float bb[8] = {0, 0, 0, 0, 0, 0, 0, 0};
  if (isA) {
    float4 b4a = *(const float4*)&bias[c0];
    float4 b4b = *(const float4*)&bias[c0 + 4];
    bb[0] = b4a.x; bb[1] = b4a.y; bb[2] = b4a.z; bb[3] = b4a.w;
    bb[4] = b4b.x; bb[5] = b4b.y; bb[6] = b4b.z; bb[7] = b4b.w;
  }
  float* dst = isA ? A : Bv;
  int cc = isA ? c0 : (c0 - COUT);
  #pragma unroll
  for (int i = 0; i < 8; ++i) {
    int m = mb + 8 * ty + i;
    *(float4*)&dst[(size_t)m * COUT + cc] =
        make_float4(acc[i][0] + bb[0], acc[i][1] + bb[1], acc[i][2] + bb[2], acc[i][3] + bb[3]);
    *(float4*)&dst[(size_t)m * COUT + cc + 4] =
        make_float4(acc[i][4] + bb[4], acc[i][5] + bb[5], acc[i][6] + bb[6], acc[i][7] + bb[7]);
  }
}

// ------------------------------------------------- gather-combine + stats
template <int COUT>
__global__ __launch_bounds__(256) void combine_k(const float* __restrict__ A,
                                                 const float* __restrict__ Bv,
                                                 const int* __restrict__ idx,
                                                 float* __restrict__ maxh,
                                                 float* __restrict__ minh,
                                                 float* __restrict__ gsum,
                                                 float* __restrict__ gsumsq) {
  constexpr int TPP = COUT / 4;
  constexpr int P = 256 / TPP;
  constexpr int PTS = 16;
  __shared__ float red[8][256];
  int tid = threadIdx.x;
  int p = tid / TPP, cq = tid % TPP;
  int b = blockIdx.x & 7, chunk = blockIdx.x >> 3;
  int nbase = b * Nn + chunk * PTS;
  const float4* A4 = (const float4*)A;
  const float4* B4 = (const float4*)Bv;
  float4 ts = make_float4(0, 0, 0, 0), ts2 = make_float4(0, 0, 0, 0);
  for (int it = 0; it < PTS / P; ++it) {
    int n = nbase + it * P + p;
    float4 a  = A4[(size_t)n * TPP + cq];
    float4 bc = B4[(size_t)n * TPP + cq];
    float4 base = make_float4(a.x - bc.x, a.y - bc.y, a.z - bc.z, a.w - bc.w);
    float4 mx = make_float4(-INFINITY, -INFINITY, -INFINITY, -INFINITY);
    float4 mn = make_float4(INFINITY, INFINITY, INFINITY, INFINITY);
    int gb = b * Nn;
    const int* ip = idx + (size_t)n * KNB;
    for (int k = 0; k < KNB; ++k) {
      int m = ip[k];
      float4 bn = B4[(size_t)(gb + m) * TPP + cq];
      float4 h = make_float4(base.x + bn.x, base.y + bn.y, base.z + bn.z, base.w + bn.w);
      mx.x = fmaxf(mx.x, h.x); mx.y = fmaxf(mx.y, h.y);
      mx.z = fmaxf(mx.z, h.z); mx.w = fmaxf(mx.w, h.w);
      mn.x = fminf(mn.x, h.x); mn.y = fminf(mn.y, h.y);
      mn.z = fminf(mn.z, h.z); mn.w = fminf(mn.w, h.w);
      ts.x += h.x; ts.y += h.y; ts.z += h.z; ts.w += h.w;
      ts2.x += h.x * h.x; ts2.y += h.y * h.y; ts2.z += h.z * h.z; ts2.w += h.w * h.w;
    }
    ((float4*)maxh)[(size_t)n * TPP + cq] = mx;
    ((float4*)minh)[(size_t)n * TPP + cq] = mn;
  }
  red[0][tid] = ts.x;  red[1][tid] = ts.y;  red[2][tid] = ts.z;  red[3][tid] = ts.w;
  red[4][tid] = ts2.x; red[5][tid] = ts2.y; red[6][tid] = ts2.z; red[7][tid] = ts2.w;
  __syncthreads();
  if (tid < COUT) {
    int q = tid & 3, g = tid >> 2;
    float s = 0.f, s2 = 0.f;
    for (int pp = 0; pp < P; ++pp) {
      int t2 = pp * TPP + g;
      s += red[q][t2]; s2 += red[4 + q][t2];
    }
    atomicAdd(&gsum[tid], s);
    atomicAdd(&gsumsq[tid], s2);
  }
}

// ------------------------------------------------- BN scale/shift per channel
__global__ void stats_k(const float* __restrict__ gsum, const float* __restrict__ gsumsq,
                        const float* __restrict__ gamma, const float* __restrict__ beta,
                        float* __restrict__ sA, float* __restrict__ sB, int COUT) {
  int c = threadIdx.x;
  if (c < COUT) {
    const float cnt = (float)((size_t)Bb * Nn * KNB);
    float mean = gsum[c] / cnt;
    float var = gsumsq[c] / cnt - mean * mean;
    var = fmaxf(var, 0.f);
    float s = gamma[c] * rsqrtf(var + EPSBN);
    sA[c] = s;
    sB[c] = beta[c] - mean * s;
  }
}

// ------------------------------------------------- apply BN+ReLU
__global__ __launch_bounds__(256) void apply_k(const float* __restrict__ maxh,
                                               const float* __restrict__ minh,
                                               const float* __restrict__ sA,
                                               const float* __restrict__ sB,
                                               float* __restrict__ out, int COUT) {
  int i = blockIdx.x * 256 + threadIdx.x;
  if (i >= NPT * COUT) return;
  int c = i % COUT;
  float s = sA[c];
  float h = (s >= 0.f) ? maxh[i] : minh[i];
  out[i] = fmaxf(s * h + sB[c], 0.f);
}

// ------------------------------------------------- global max pool over N
__global__ __launch_bounds__(256) void gmax_k(const float* __restrict__ feat,
                                              unsigned* __restrict__ pooled) {
  int b = blockIdx.y, chunk = blockIdx.x;
  int c = threadIdx.x;
  const float* fb = feat + ((size_t)b * Nn + chunk * 32) * 256;
  float m = 0.f;
  #pragma unroll 8
  for (int r = 0; r < 32; ++r) m = fmaxf(m, fb[(size_t)r * 256 + c]);
  atomicMax(&pooled[b * 256 + c], __float_as_uint(m));
}

// ------------------------------------------------- final linear 8x256 @ 256x256
__global__ void final_k(const float* __restrict__ pooled, const float* __restrict__ wo,
                        const float* __restrict__ bo, float* __restrict__ out) {
  int b = blockIdx.x, c = threadIdx.x;
  const float* pr = pooled + b * 256;
  const float* wr = wo + c * 256;
  float s = bo[c];
  for (int j = 0; j < 256; ++j) s += pr[j] * wr[j];
  out[b * 256 + c] = s;
}

// ------------------------------------------------- layer driver
template <int CIN, int COUT>
static void run_layer(const float* fin, const float* W, const float* bias,
                      const float* gamma, const float* beta, float* fout,
                      float* Abuf, float* Bvbuf, int* idxb, float* xx,
                      float* maxh, float* minh, float* gsum,
                      float* sA, float* sB, hipStream_t stream) {
  constexpr int KP = ((CIN + 15) / 16) * 16;
  row_sumsq_k<<<(NPT + 255) / 256, 256, 0, stream>>>(fin, xx, CIN);
  knn_k<CIN, KP><<<512, 256, 0, stream>>>(fin, xx, idxb);
  gemmAB_k<<<dim3(2 * COUT / 128, NPT / 128), 256, 0, stream>>>(fin, W, bias,
                                                                Abuf, Bvbuf, COUT, CIN);
  hipMemsetAsync(gsum, 0, 2 * 256 * sizeof(float), stream);
  combine_k<COUT><<<NPT / 16, 256, 0, stream>>>(Abuf, Bvbuf, idxb, maxh, minh,
                                                gsum, gsum + 256);
  stats_k<<<1, 256, 0, stream>>>(gsum, gsum + 256, gamma, beta, sA, sB, COUT);
  apply_k<<<(NPT * COUT + 255) / 256, 256, 0, stream>>>(maxh, minh, sA, sB, fout, COUT);
}

extern "C" void kernel_launch(void* const* d_in, const int* in_sizes, int n_in,
                              void* d_out, int out_size, void* d_ws, size_t ws_size,
                              hipStream_t stream) {
  const float* x   = (const float*)d_in[0];
  const float* w1  = (const float*)d_in[1];
  const float* b1  = (const float*)d_in[2];
  const float* g1  = (const float*)d_in[3];
  const float* be1 = (const float*)d_in[4];
  const float* w2  = (const float*)d_in[5];
  const float* b2  = (const float*)d_in[6];
  const float* g2  = (const float*)d_in[7];
  const float* be2 = (const float*)d_in[8];
  const float* w3  = (const float*)d_in[9];
  const float* b3  = (const float*)d_in[10];
  const float* g3  = (const float*)d_in[11];
  const float* be3 = (const float*)d_in[12];
  const float* wo  = (const float*)d_in[13];
  const float* bo  = (const float*)d_in[14];
  float* out = (float*)d_out;

  // Workspace ~81 MB (kNN fused: no nd matrix).
  char* ws = (char*)d_ws;
  size_t off = 0;
  auto grab = [&](size_t bytes) -> char* {
    char* p = ws + off;
    off = (off + bytes + 255) & ~(size_t)255;
    return p;
  };
  const size_t SLAB = (size_t)NPT * 256 * 4;          // 16.78 MB
  float* Abuf  = (float*)grab(SLAB);
  float* Bvbuf = (float*)grab(SLAB);
  int*   idxb  = (int*)  grab((size_t)NPT * KNB * 4);
  float* xx    = (float*)grab((size_t)NPT * 4);
  float* feat1 = (float*)grab((size_t)NPT * 64 * 4);
  float* feat2 = (float*)grab((size_t)NPT * 128 * 4);
  float* maxh  = (float*)grab(SLAB);
  float* minh  = (float*)grab(SLAB);
  float* feat3 = minh;   // apply reads minh[i] then writes feat3[i]: safe alias
  float* gsum  = (float*)grab(2 * 256 * 4);
  float* sA    = (float*)grab(256 * 4);
  float* sB    = (float*)grab(256 * 4);
  unsigned* pooled = (unsigned*)grab(Bb * 256 * 4);

  run_layer<3, 64>(x, w1, b1, g1, be1, feat1, Abuf, Bvbuf, idxb, xx,
                   maxh, minh, gsum, sA, sB, stream);
  run_layer<64, 128>(feat1, w2, b2, g2, be2, feat2, Abuf, Bvbuf, idxb, xx,
                     maxh, minh, gsum, sA, sB, stream);
  run_layer<128, 256>(feat2, w3, b3, g3, be3, feat3, Abuf, Bvbuf, idxb, xx,
                      maxh, minh, gsum, sA, sB, stream);

  hipMemsetAsync(pooled, 0, Bb * 256 * sizeof(unsigned), stream);
  gmax_k<<<dim3(Nn / 32, Bb), 256, 0, stream>>>(feat3, pooled);
  final_k<<<Bb, 256, 0, stream>>>((const float*)pooled, wo, bo, out);
  (void)in_sizes; (void)n_in; (void)out_size; (void)ws_size;
}

// Round 11
// 893.547 us; speedup vs baseline: 13.0024x; 3.8587x over previous
//
#include <hip/hip_runtime.h>
#include <cmath>

// DGCNN: B=8, N=2048, k=20, dims 3->64->128->256, fp32 throughout.
static constexpr int Bb  = 8;
static constexpr int Nn  = 2048;
static constexpr int KNB = 20;
static constexpr int NPT = Bb * Nn;
#define EPSBN 1e-5f

// LDS column swizzle: maps 4-float groups so 16-address b128 reads cover all
// 32 banks 2x (2-way = free) instead of 4 bank-groups 4x.
__device__ __forceinline__ int permc(int c) { return c ^ (4 * (c >> 5)); }

// ---------------------------------------------------------------- row |x|^2
__global__ __launch_bounds__(256) void row_sumsq_k(const float* __restrict__ f,
                                                   float* __restrict__ xx, int C) {
  int g = blockIdx.x * 256 + threadIdx.x;
  if (g >= NPT) return;
  const float* r = f + (size_t)g * C;
  float s = 0.f;
  for (int j = 0; j < C; ++j) { float v = r[j]; s += v * v; }
  xx[g] = s;
}

// ------------------------------------------------- neg_dist, symmetric 128x128
// nd[n][m] = 2*x_n.x_m - |x_n|^2 - |x_m|^2 ; diag forced to exactly 0.
// Upper-triangular block pairs (136/batch); mirror via 32-row LDS transpose
// chunks (buffer unioned with dead As/Bs -> 16.9 KB).
// XCD swizzle (big path): 1D grid 1088, batch = blockIdx.x & 7 so each XCD's
// L2 keeps one batch's feature slab resident across the ~17 tile re-reads.
// HARD-LEARNED (R6/R7): (a) do NOT set launch_bounds min-waves — acc[8][8]
// needs >=64 VGPR; forcing 4 waves/SIMD spilled to scratch (FETCH 37->412 MB).
// (b) do NOT index acc[][] with runtime values — dynamic register indexing
// demotes the array to scratch (R7: VGPR=52, 13 GB scratch traffic, 20x).
// (R9/R10): no serial single-lane LDS selection; no per-group divergent
// long loops — fusion attempts stalled 90%+ on these.
__global__ __launch_bounds__(256) void dist_k(const float* __restrict__ f,
                                              const float* __restrict__ xx,
                                              float* __restrict__ nd, int C) {
  __shared__ float lds[32 * 132];                       // 16.9 KB, unioned
  float (*As)[132] = (float(*)[132])lds;                // rows 0..15
  float (*Bs)[132] = (float(*)[132])(lds + 16 * 132);   // rows 16..31
  float* Sc = lds;                                      // transpose buf (32x132)
  int tid = threadIdx.x, tx = tid & 15, ty = tid >> 4;
  int b, p;
  if (gridDim.x == 136 * Bb) { b = blockIdx.x & 7; p = blockIdx.x >> 3; }
  else                       { b = blockIdx.z;     p = blockIdx.x; }
  const float* fb  = f  + (size_t)b * Nn * C;
  const float* xxb = xx + (size_t)b * Nn;
  float* ndb = nd + (size_t)b * Nn * Nn;
  // triangular decode: p in [0,136) -> (rblk, cblk), rblk <= cblk
  int rblk = 0;
  while (p >= 16 - rblk) { p -= 16 - rblk; ++rblk; }
  int rb = rblk * 128, cb = (rblk + p) * 128;
  bool diag = (rb == cb);
  int kk0 = tid & 15, rr = tid >> 4;
  float acc[8][8] = {};
  for (int k0 = 0; k0 < C; k0 += 16) {
    int k = k0 + kk0;
    bool ok = k < C;
    #pragma unroll
    for (int t = 0; t < 8; ++t) {
      int r2 = rr + 16 * t;
      int c2 = permc(r2);
      As[kk0][c2] = ok ? fb[(size_t)(rb + r2) * C + k] : 0.f;
      Bs[kk0][c2] = ok ? fb[(size_t)(cb + r2) * C + k] : 0.f;
    }
    __syncthreads();
    #pragma unroll
    for (int kk = 0; kk < 16; ++kk) {
      float4 a0 = *(const float4*)&As[kk][permc(8 * ty)];
      float4 a1 = *(const float4*)&As[kk][permc(8 * ty + 4)];
      float4 b0 = *(const float4*)&Bs[kk][permc(8 * tx)];
      float4 b1 = *(const float4*)&Bs[kk][permc(8 * tx + 4)];
      float av[8] = {a0.x, a0.y, a0.z, a0.w, a1.x, a1.y, a1.z, a1.w};
      float bv[8] = {b0.x, b0.y, b0.z, b0.w, b1.x, b1.y, b1.z, b1.w};
      #pragma unroll
      for (int i = 0; i < 8; ++i)
        #pragma unroll
        for (int j = 0; j < 8; ++j) acc[i][j] += av[i] * bv[j];
    }
    __syncthreads();
  }
  // epilogue: finalize into acc, store tile (+ mirrored tile if off-diag)
  float xr[8], xc[8];
  #pragma unroll
  for (int i = 0; i < 8; ++i) xr[i] = xxb[rb + 8 * ty + i];
  #pragma unroll
  for (int j = 0; j < 8; ++j) xc[j] = xxb[cb + 8 * tx + j];
  #pragma unroll
  for (int i = 0; i < 8; ++i) {
    int grow = rb + 8 * ty + i;
    #pragma unroll
    for (int j = 0; j < 8; ++j) {
      int gcol = cb + 8 * tx + j;
      float v = 2.f * acc[i][j] - xr[i] - xc[j];
      acc[i][j] = (grow == gcol) ? 0.f : v;
    }
    *(float4*)&ndb[(size_t)grow * Nn + cb + 8 * tx] =
        make_float4(acc[i][0], acc[i][1], acc[i][2], acc[i][3]);
    *(float4*)&ndb[(size_t)grow * Nn + cb + 8 * tx + 4] =
        make_float4(acc[i][4], acc[i][5], acc[i][6], acc[i][7]);
  }
  if (!diag) {
    int lr = tid >> 3, q8 = tid & 7;
    #pragma unroll
    for (int h = 0; h < 4; ++h) {
      __syncthreads();
      if ((tx >> 2) == h) {
        int txl = tx & 3;
        #pragma unroll
        for (int j = 0; j < 8; ++j)
          #pragma unroll
          for (int i = 0; i < 8; ++i)
            Sc[(8 * txl + j) * 132 + 8 * ty + i] = acc[i][j];
      }
      __syncthreads();
      int grow = cb + 32 * h + lr;
      #pragma unroll
      for (int u = 0; u < 4; ++u) {
        float4 v = *(const float4*)&Sc[lr * 132 + 4 * (q8 + 8 * u)];
        *(float4*)&ndb[(size_t)grow * Nn + rb + 4 * (q8 + 8 * u)] = v;
      }
    }
  }
}

// ------------------------------------------------- wave0 suffix-scan digit find
__device__ __forceinline__ void find_digit64(const int* hist, int tid,
                                             int* s_digit, int* s_kneed) {
  if (tid < 64) {
    int kneed = *s_kneed;
    int l = tid;
    int h0 = hist[4 * l], h1 = hist[4 * l + 1], h2 = hist[4 * l + 2], h3 = hist[4 * l + 3];
    int s3 = h3, s2 = h2 + s3, s1 = h1 + s2, s0 = h0 + s1;
    int cum = s0;
    #pragma unroll
    for (int off = 1; off < 64; off <<= 1) {
      int v = __shfl_down(cum, off, 64);
      if (l + off < 64) cum += v;
    }
    int ab = cum - s0;
    int suf0 = ab + s0, suf1 = ab + s1, suf2 = ab + s2, suf3 = ab + s3, suf4 = ab;
    if (suf0 >= kneed && suf1 < kneed) { *s_digit = 4 * l;     *s_kneed = kneed - suf1; }
    if (suf1 >= kneed && suf2 < kneed) { *s_digit = 4 * l + 1; *s_kneed = kneed - suf2; }
    if (suf2 >= kneed && suf3 < kneed) { *s_digit = 4 * l + 2; *s_kneed = kneed - suf3; }
    if (suf3 >= kneed && suf4 < kneed) { *s_digit = 4 * l + 3; *s_kneed = kneed - suf4; }
  }
}

// ------------------------------------------------- top-20: radix select per row
__global__ __launch_bounds__(256) void topk_k(const float* __restrict__ nd,
                                              int* __restrict__ outidx) {
  __shared__ unsigned keys[Nn];
  __shared__ unsigned ck[Nn];
  __shared__ short cidx[Nn];
  __shared__ int hist[256];
  __shared__ int s_digit, s_kneed, s_cnt, s_ncand;
  int tid = threadIdx.x;
  const float* row = nd + (size_t)blockIdx.x * Nn;
  int* orow = outidx + (size_t)blockIdx.x * KNB;
  if (tid == 0) { s_kneed = KNB; s_cnt = 0; s_ncand = 0; }
  hist[tid] = 0;
  __syncthreads();
  #pragma unroll
  for (int t = 0; t < Nn / 256; ++t) {
    int i = tid + 256 * t;
    unsigned u = __float_as_uint(row[i]);
    unsigned k = (u & 0x80000000u) ? ~u : (u | 0x80000000u);
    keys[i] = k;
    atomicAdd(&hist[k >> 24], 1);
  }
  __syncthreads();
  find_digit64(hist, tid, &s_digit, &s_kneed);
  __syncthreads();
  unsigned dig1 = (unsigned)s_digit;
  unsigned prefix = dig1 << 24;
  #pragma unroll
  for (int t = 0; t < Nn / 256; ++t) {
    int i = tid + 256 * t;
    unsigned k = keys[i];
    unsigned bb = k >> 24;
    if (bb > dig1) { int p = atomicAdd(&s_cnt, 1); orow[p] = i; }
    else if (bb == dig1) { int p = atomicAdd(&s_ncand, 1); ck[p] = k; cidx[p] = (short)i; }
  }
  __syncthreads();
  int nc = s_ncand;
  for (int shift = 16; shift >= 0; shift -= 8) {
    unsigned pm = 0xFFFFFFFFu << (shift + 8);
    hist[tid] = 0;
    __syncthreads();
    for (int j = tid; j < nc; j += 256) {
      unsigned k = ck[j];
      if (((k ^ prefix) & pm) == 0) atomicAdd(&hist[(k >> shift) & 255], 1);
    }
    __syncthreads();
    find_digit64(hist, tid, &s_digit, &s_kneed);
    __syncthreads();
    prefix |= ((unsigned)s_digit) << shift;
  }
  unsigned T = prefix;
  for (int j = tid; j < nc; j += 256)
    if (ck[j] > T) { int p = atomicAdd(&s_cnt, 1); orow[p] = (int)cidx[j]; }
  int kF = s_kneed, base = KNB - kF, last = -1;
  for (int r = 0; r < kF; ++r) {
    int loc = 0x7fffffff;
    for (int j = tid; j < nc; j += 256)
      if (ck[j] == T && (int)cidx[j] > last) loc = min(loc, (int)cidx[j]);
    hist[tid] = loc;
    __syncthreads();
    for (int s = 128; s > 0; s >>= 1) {
      if (tid < s) hist[tid] = min(hist[tid], hist[tid + s]);
      __syncthreads();
    }
    last = hist[0];
    if (tid == 0) orow[base + r] = last;
    __syncthreads();
  }
}

// ------------------------------------------------- fused GEMM: A = X*W1^T + b, Bv = X*W2^T
__global__ __launch_bounds__(256) void gemmAB_k(const float* __restrict__ X,
                                                const float* __restrict__ W,
                                                const float* __restrict__ bias,
                                                float* __restrict__ A,
                                                float* __restrict__ Bv,
                                                int COUT, int CIN) {
  __shared__ float Xs[16][132];
  __shared__ float Ws[16][132];
  int tid = threadIdx.x, tx = tid & 15, ty = tid >> 4;
  int mb = blockIdx.y * 128, cb = blockIdx.x * 128;
  int kk0 = tid & 15, rr = tid >> 4;
  int ldw = 2 * CIN;
  float acc[8][8] = {};
  for (int k0 = 0; k0 < CIN; k0 += 16) {
    int k = k0 + kk0;
    bool ok = k < CIN;
    #pragma unroll
    for (int r2 = rr; r2 < 128; r2 += 16) {
      Xs[kk0][permc(r2)] = ok ? X[(size_t)(mb + r2) * CIN + k] : 0.f;
      int c2 = cb + r2;
      const float* wr = (c2 < COUT) ? (W + (size_t)c2 * ldw)
                                    : (W + (size_t)(c2 - COUT) * ldw + CIN);
      Ws[kk0][permc(r2)] = ok ? wr[k] : 0.f;
    }
    __syncthreads();
    #pragma unroll
    for (int kk = 0; kk < 16; ++kk) {
      float4 a0 = *(const float4*)&Xs[kk][permc(8 * ty)];
      float4 a1 = *(const float4*)&Xs[kk][permc(8 * ty + 4)];
      float4 b0 = *(const float4*)&Ws[kk][permc(8 * tx)];
      float4 b1 = *(const float4*)&Ws[kk][permc(8 * tx + 4)];
      float av[8] = {a0.x, a0.y, a0.z, a0.w, a1.x, a1.y, a1.z, a1.w};
      float bv[8] = {b0.x, b0.y, b0.z, b0.w, b1.x, b1.y, b1.z, b1.w};
      #pragma unroll
      for (int i = 0; i < 8; ++i)
        #pragma unroll
        for (int j = 0; j < 8; ++j) acc[i][j] += av[i] * bv[j];
    }
    __syncthreads();
  }
  int c0 = cb + 8 * tx;
  bool isA = (c0 < COUT);
  float bb[8] = {0, 0, 0, 0, 0, 0, 0, 0};
  if (isA) {
    float4 b4a = *(const float4*)&bias[c0];
    float4 b4b = *(const float4*)&bias[c0 + 4];
    bb[0] = b4a.x; bb[1] = b4a.y; bb[2] = b4a.z; bb[3] = b4a.w;
    bb[4] = b4b.x; bb[5] = b4b.y; bb[6] = b4b.z; bb[7] = b4b.w;
  }
  float* dst = isA ? A : Bv;
  int cc = isA ? c0 : (c0 - COUT);
  #pragma unroll
  for (int i = 0; i < 8; ++i) {
    int m = mb + 8 * ty + i;
    *(float4*)&dst[(size_t)m * COUT + cc] =
        make_float4(acc[i][0] + bb[0], acc[i][1] + bb[1], acc[i][2] + bb[2], acc[i][3] + bb[3]);
    *(float4*)&dst[(size_t)m * COUT + cc + 4] =
        make_float4(acc[i][4] + bb[4], acc[i][5] + bb[5], acc[i][6] + bb[6], acc[i][7] + bb[7]);
  }
}

// ------------------------------------------------- gather-combine + stats
// XCD-aware: batch = blockIdx.x % 8 so each XCD's L2 caches one batch's Bv slice.
template <int COUT>
__global__ __launch_bounds__(256) void combine_k(const float* __restrict__ A,
                                                 const float* __restrict__ Bv,
                                                 const int* __restrict__ idx,
                                                 float* __restrict__ maxh,
                                                 float* __restrict__ minh,
                                                 float* __restrict__ gsum,
                                                 float* __restrict__ gsumsq) {
  constexpr int TPP = COUT / 4;
  constexpr int P = 256 / TPP;
  constexpr int PTS = 16;
  __shared__ float red[8][256];
  int tid = threadIdx.x;
  int p = tid / TPP, cq = tid % TPP;
  int b = blockIdx.x & 7, chunk = blockIdx.x >> 3;
  int nbase = b * Nn + chunk * PTS;
  const float4* A4 = (const float4*)A;
  const float4* B4 = (const float4*)Bv;
  float4 ts = make_float4(0, 0, 0, 0), ts2 = make_float4(0, 0, 0, 0);
  for (int it = 0; it < PTS / P; ++it) {
    int n = nbase + it * P + p;
    float4 a  = A4[(size_t)n * TPP + cq];
    float4 bc = B4[(size_t)n * TPP + cq];
    float4 base = make_float4(a.x - bc.x, a.y - bc.y, a.z - bc.z, a.w - bc.w);
    float4 mx = make_float4(-INFINITY, -INFINITY, -INFINITY, -INFINITY);
    float4 mn = make_float4(INFINITY, INFINITY, INFINITY, INFINITY);
    int gb = b * Nn;
    const int* ip = idx + (size_t)n * KNB;
    for (int k = 0; k < KNB; ++k) {
      int m = ip[k];
      float4 bn = B4[(size_t)(gb + m) * TPP + cq];
      float4 h = make_float4(base.x + bn.x, base.y + bn.y, base.z + bn.z, base.w + bn.w);
      mx.x = fmaxf(mx.x, h.x); mx.y = fmaxf(mx.y, h.y);
      mx.z = fmaxf(mx.z, h.z); mx.w = fmaxf(mx.w, h.w);
      mn.x = fminf(mn.x, h.x); mn.y = fminf(mn.y, h.y);
      mn.z = fminf(mn.z, h.z); mn.w = fminf(mn.w, h.w);
      ts.x += h.x; ts.y += h.y; ts.z += h.z; ts.w += h.w;
      ts2.x += h.x * h.x; ts2.y += h.y * h.y; ts2.z += h.z * h.z; ts2.w += h.w * h.w;
    }
    ((float4*)maxh)[(size_t)n * TPP + cq] = mx;
    ((float4*)minh)[(size_t)n * TPP + cq] = mn;
  }
  red[0][tid] = ts.x;  red[1][tid] = ts.y;  red[2][tid] = ts.z;  red[3][tid] = ts.w;
  red[4][tid] = ts2.x; red[5][tid] = ts2.y; red[6][tid] = ts2.z; red[7][tid] = ts2.w;
  __syncthreads();
  if (tid < COUT) {
    int q = tid & 3, g = tid >> 2;
    float s = 0.f, s2 = 0.f;
    for (int pp = 0; pp < P; ++pp) {
      int t2 = pp * TPP + g;
      s += red[q][t2]; s2 += red[4 + q][t2];
    }
    atomicAdd(&gsum[tid], s);
    atomicAdd(&gsumsq[tid], s2);
  }
}

// ------------------------------------------------- BN scale/shift per channel
__global__ void stats_k(const float* __restrict__ gsum, const float* __restrict__ gsumsq,
                        const float* __restrict__ gamma, const float* __restrict__ beta,
                        float* __restrict__ sA, float* __restrict__ sB, int COUT) {
  int c = threadIdx.x;
  if (c < COUT) {
    const float cnt = (float)((size_t)Bb * Nn * KNB);
    float mean = gsum[c] / cnt;
    float var = gsumsq[c] / cnt - mean * mean;
    var = fmaxf(var, 0.f);
    float s = gamma[c] * rsqrtf(var + EPSBN);
    sA[c] = s;
    sB[c] = beta[c] - mean * s;
  }
}

// ------------------------------------------------- apply BN+ReLU (layers 1,2)
__global__ __launch_bounds__(256) void apply_k(const float* __restrict__ maxh,
                                               const float* __restrict__ minh,
                                               const float* __restrict__ sA,
                                               const float* __restrict__ sB,
                                               float* __restrict__ out, int COUT) {
  int i = blockIdx.x * 256 + threadIdx.x;
  if (i >= NPT * COUT) return;
  int c = i % COUT;
  float s = sA[c];
  float h = (s >= 0.f) ? maxh[i] : minh[i];
  out[i] = fmaxf(s * h + sB[c], 0.f);
}

// ------------------------------------------------- layer-3 fused BN+ReLU+pool
// Layer-3 features are consumed ONLY by the global max pool — never write
// feat3; apply BN+ReLU inline and atomicMax into pooled (post-ReLU >= 0 so
// float bits are monotone; pooled pre-zeroed).
__global__ __launch_bounds__(256) void gmax3_k(const float* __restrict__ maxh,
                                               const float* __restrict__ minh,
                                               const float* __restrict__ sA,
                                               const float* __restrict__ sB,
                                               unsigned* __restrict__ pooled) {
  int b = blockIdx.y, chunk = blockIdx.x;
  int c = threadIdx.x;
  float s = sA[c], t = sB[c];
  const float* src = (s >= 0.f) ? maxh : minh;
  const float* fb = src + ((size_t)b * Nn + chunk * 32) * 256;
  float m = 0.f;
  #pragma unroll 8
  for (int r = 0; r < 32; ++r) m = fmaxf(m, fmaxf(s * fb[(size_t)r * 256 + c] + t, 0.f));
  atomicMax(&pooled[b * 256 + c], __float_as_uint(m));
}

// ------------------------------------------------- final linear 8x256 @ 256x256
__global__ void final_k(const float* __restrict__ pooled, const float* __restrict__ wo,
                        const float* __restrict__ bo, float* __restrict__ out) {
  int b = blockIdx.x, c = threadIdx.x;
  const float* pr = pooled + b * 256;
  const float* wr = wo + c * 256;
  float s = bo[c];
  for (int j = 0; j < 256; ++j) s += pr[j] * wr[j];
  out[b * 256 + c] = s;
}

// ------------------------------------------------- layer driver
template <int CIN, int COUT, bool LAST>
static void run_layer(const float* fin, const float* W, const float* bias,
                      const float* gamma, const float* beta, float* fout,
                      float* nd, bool big, float* Abuf, float* Bvbuf, int* idxb,
                      float* xx, float* maxh, float* minh, float* gsum,
                      float* sA, float* sB, unsigned* pooled, hipStream_t stream) {
  row_sumsq_k<<<(NPT + 255) / 256, 256, 0, stream>>>(fin, xx, CIN);
  if (big) {
    dist_k<<<dim3(136 * Bb), 256, 0, stream>>>(fin, xx, nd, CIN);
    topk_k<<<NPT, 256, 0, stream>>>(nd, idxb);
  } else {
    for (int b = 0; b < Bb; ++b) {
      dist_k<<<dim3(136, 1, 1), 256, 0, stream>>>(
          fin + (size_t)b * Nn * CIN, xx + (size_t)b * Nn, nd, CIN);
      topk_k<<<Nn, 256, 0, stream>>>(nd, idxb + (size_t)b * Nn * KNB);
    }
  }
  gemmAB_k<<<dim3(2 * COUT / 128, NPT / 128), 256, 0, stream>>>(fin, W, bias,
                                                                Abuf, Bvbuf, COUT, CIN);
  hipMemsetAsync(gsum, 0, 2 * 256 * sizeof(float), stream);
  combine_k<COUT><<<NPT / 16, 256, 0, stream>>>(Abuf, Bvbuf, idxb, maxh, minh,
                                                gsum, gsum + 256);
  stats_k<<<1, 256, 0, stream>>>(gsum, gsum + 256, gamma, beta, sA, sB, COUT);
  if (LAST) {
    gmax3_k<<<dim3(Nn / 32, Bb), 256, 0, stream>>>(maxh, minh, sA, sB, pooled);
  } else {
    apply_k<<<(NPT * COUT + 255) / 256, 256, 0, stream>>>(maxh, minh, sA, sB, fout, COUT);
  }
}

extern "C" void kernel_launch(void* const* d_in, const int* in_sizes, int n_in,
                              void* d_out, int out_size, void* d_ws, size_t ws_size,
                              hipStream_t stream) {
  const float* x   = (const float*)d_in[0];
  const float* w1  = (const float*)d_in[1];
  const float* b1  = (const float*)d_in[2];
  const float* g1  = (const float*)d_in[3];
  const float* be1 = (const float*)d_in[4];
  const float* w2  = (const float*)d_in[5];
  const float* b2  = (const float*)d_in[6];
  const float* g2  = (const float*)d_in[7];
  const float* be2 = (const float*)d_in[8];
  const float* w3  = (const float*)d_in[9];
  const float* b3  = (const float*)d_in[10];
  const float* g3  = (const float*)d_in[11];
  const float* be3 = (const float*)d_in[12];
  const float* wo  = (const float*)d_in[13];
  const float* bo  = (const float*)d_in[14];
  float* out = (float*)d_out;

  char* ws = (char*)d_ws;
  size_t off = 0;
  auto grab = [&](size_t bytes) -> char* {
    char* p = ws + off;
    off = (off + bytes + 255) & ~(size_t)255;
    return p;
  };
  const size_t SLAB = (size_t)NPT * 256 * 4;          // 16.78 MB
  const size_t ND_ALL = (size_t)Bb * Nn * Nn * 4;     // 134.2 MB
  const size_t NEED_BIG = ND_ALL + ((size_t)NPT * KNB * 4) + ((size_t)NPT * 4) +
                          ((size_t)NPT * 64 * 4) + ((size_t)NPT * 128 * 4) +
                          (16 << 10) + 16 * 256;
  bool big = (ws_size >= NEED_BIG);

  float *nd, *Abuf, *Bvbuf, *maxh, *minh;
  if (big) {
    nd    = (float*)grab(ND_ALL);
    Abuf  = nd;
    Bvbuf = (float*)((char*)nd + SLAB);
    maxh  = (float*)((char*)nd + 2 * SLAB);
    minh  = (float*)((char*)nd + 3 * SLAB);
  } else {
    nd    = (float*)grab((size_t)Nn * Nn * 4);
    Abuf  = nd;
    Bvbuf = (float*)grab(SLAB);
    maxh  = nullptr; minh = nullptr;
  }
  int*   idxb  = (int*)  grab((size_t)NPT * KNB * 4);
  float* xx    = (float*)grab((size_t)NPT * 4);
  float* feat1 = (float*)grab((size_t)NPT * 64 * 4);
  float* feat2 = (float*)grab((size_t)NPT * 128 * 4);
  if (!big) {
    maxh = (float*)grab(SLAB);
    minh = (float*)grab(SLAB);
  }
  float* gsum  = (float*)grab(2 * 256 * 4);
  float* sA    = (float*)grab(256 * 4);
  float* sB    = (float*)grab(256 * 4);
  unsigned* pooled = (unsigned*)grab(Bb * 256 * 4);

  hipMemsetAsync(pooled, 0, Bb * 256 * sizeof(unsigned), stream);

  run_layer<3, 64, false>(x, w1, b1, g1, be1, feat1, nd, big, Abuf, Bvbuf, idxb, xx,
                          maxh, minh, gsum, sA, sB, pooled, stream);
  run_layer<64, 128, false>(feat1, w2, b2, g2, be2, feat2, nd, big, Abuf, Bvbuf, idxb, xx,
                            maxh, minh, gsum, sA, sB, pooled, stream);
  run_layer<128, 256, true>(feat2, w3, b3, g3, be3, nullptr, nd, big, Abuf, Bvbuf, idxb, xx,
                            maxh, minh, gsum, sA, sB, pooled, stream);

  final_k<<<Bb, 256, 0, stream>>>((const float*)pooled, wo, bo, out);
  (void)in_sizes; (void)n_in; (void)out_size;
}

// Round 12
// 827.290 us; speedup vs baseline: 14.0438x; 1.0801x over previous
//
#include <hip/hip_runtime.h>
#include <cmath>

// DGCNN: B=8, N=2048, k=20, dims 3->64->128->256, fp32 throughout.
static constexpr int Bb  = 8;
static constexpr int Nn  = 2048;
static constexpr int KNB = 20;
static constexpr int NPT = Bb * Nn;
#define EPSBN 1e-5f

// LDS column swizzle: maps 4-float groups so 16-address b128 reads cover all
// 32 banks 2x (2-way = free) instead of 4 bank-groups 4x.
__device__ __forceinline__ int permc(int c) { return c ^ (4 * (c >> 5)); }

// ---------------------------------------------------------------- row |x|^2
__global__ __launch_bounds__(256) void row_sumsq_k(const float* __restrict__ f,
                                                   float* __restrict__ xx, int C) {
  int g = blockIdx.x * 256 + threadIdx.x;
  if (g >= NPT) return;
  const float* r = f + (size_t)g * C;
  float s = 0.f;
  if ((C & 3) == 0) {
    const float4* r4 = (const float4*)r;
    for (int j = 0; j < C / 4; ++j) {
      float4 v = r4[j];
      s += v.x * v.x + v.y * v.y + v.z * v.z + v.w * v.w;
    }
  } else {
    for (int j = 0; j < C; ++j) { float v = r[j]; s += v * v; }
  }
  xx[g] = s;
}

// ------------------------------------------------- neg_dist, symmetric 128x128
// nd[n][m] = 2*x_n.x_m - |x_n|^2 - |x_m|^2 ; diag forced to exactly 0.
// Upper-triangular block pairs (136/batch); mirror via 32-row LDS transpose
// chunks (unioned with dead As/Bs -> 16.9 KB). XCD swizzle (big path):
// batch = blockIdx.x & 7 so each XCD's L2 keeps one batch's feature slab
// resident (R11: FETCH 37.9 -> 8.6 MB). Register prefetch of next K-panel
// (R5 structure; safe now that LDS is 16.9 KB not 33.8). Sc transpose stores
// parity-swapped by txl&1 with STATIC register indices in both branches:
// bank bases spread {0,4,..,28} -> 2-way (free) instead of 4-way; reader
// un-swaps via address XOR 4 (addresses runtime-OK, register indices not).
// HARD-LEARNED (R6/R7): no launch_bounds min-waves (acc[8][8] needs >=64
// VGPR; forcing 4/SIMD spilled: FETCH 37->412 MB); no runtime-indexed
// register arrays (R7: demoted to scratch, 13 GB traffic). (R9/R10): no
// serial single-lane LDS selection / divergent long loops in fused kNN.
__global__ __launch_bounds__(256) void dist_k(const float* __restrict__ f,
                                              const float* __restrict__ xx,
                                              float* __restrict__ nd, int C) {
  __shared__ float lds[32 * 132];                       // 16.9 KB, unioned
  float (*As)[132] = (float(*)[132])lds;                // rows 0..15
  float (*Bs)[132] = (float(*)[132])(lds + 16 * 132);   // rows 16..31
  float* Sc = lds;                                      // transpose buf (32x132)
  int tid = threadIdx.x, tx = tid & 15, ty = tid >> 4;
  int b, p;
  if (gridDim.x == 136 * Bb) { b = blockIdx.x & 7; p = blockIdx.x >> 3; }
  else                       { b = blockIdx.z;     p = blockIdx.x; }
  const float* fb  = f  + (size_t)b * Nn * C;
  const float* xxb = xx + (size_t)b * Nn;
  float* ndb = nd + (size_t)b * Nn * Nn;
  // triangular decode: p in [0,136) -> (rblk, cblk), rblk <= cblk
  int rblk = 0;
  while (p >= 16 - rblk) { p -= 16 - rblk; ++rblk; }
  int rb = rblk * 128, cb = (rblk + p) * 128;
  bool diag = (rb == cb);
  int kk0 = tid & 15, rr = tid >> 4;
  float acc[8][8] = {};
  float pa[8], pb[8];
  {
    bool ok = kk0 < C;
    #pragma unroll
    for (int t = 0; t < 8; ++t) {
      int r2 = rr + 16 * t;
      pa[t] = ok ? fb[(size_t)(rb + r2) * C + kk0] : 0.f;
      pb[t] = ok ? fb[(size_t)(cb + r2) * C + kk0] : 0.f;
    }
  }
  for (int k0 = 0; k0 < C; k0 += 16) {
    __syncthreads();
    #pragma unroll
    for (int t = 0; t < 8; ++t) {
      int c2 = permc(rr + 16 * t);
      As[kk0][c2] = pa[t];
      Bs[kk0][c2] = pb[t];
    }
    __syncthreads();
    if (k0 + 16 < C) {
      int k2 = k0 + 16 + kk0;
      bool ok2 = k2 < C;
      #pragma unroll
      for (int t = 0; t < 8; ++t) {
        int r2 = rr + 16 * t;
        pa[t] = ok2 ? fb[(size_t)(rb + r2) * C + k2] : 0.f;
        pb[t] = ok2 ? fb[(size_t)(cb + r2) * C + k2] : 0.f;
      }
    }
    #pragma unroll
    for (int kk = 0; kk < 16; ++kk) {
      float4 a0 = *(const float4*)&As[kk][permc(8 * ty)];
      float4 a1 = *(const float4*)&As[kk][permc(8 * ty + 4)];
      float4 b0 = *(const float4*)&Bs[kk][permc(8 * tx)];
      float4 b1 = *(const float4*)&Bs[kk][permc(8 * tx + 4)];
      float av[8] = {a0.x, a0.y, a0.z, a0.w, a1.x, a1.y, a1.z, a1.w};
      float bv[8] = {b0.x, b0.y, b0.z, b0.w, b1.x, b1.y, b1.z, b1.w};
      #pragma unroll
      for (int i = 0; i < 8; ++i)
        #pragma unroll
        for (int j = 0; j < 8; ++j) acc[i][j] += av[i] * bv[j];
    }
  }
  // epilogue: finalize into acc, store tile (+ mirrored tile if off-diag)
  float xr[8], xc[8];
  #pragma unroll
  for (int i = 0; i < 8; ++i) xr[i] = xxb[rb + 8 * ty + i];
  #pragma unroll
  for (int j = 0; j < 8; ++j) xc[j] = xxb[cb + 8 * tx + j];
  #pragma unroll
  for (int i = 0; i < 8; ++i) {
    int grow = rb + 8 * ty + i;
    #pragma unroll
    for (int j = 0; j < 8; ++j) {
      int gcol = cb + 8 * tx + j;
      float v = 2.f * acc[i][j] - xr[i] - xc[j];
      acc[i][j] = (grow == gcol) ? 0.f : v;
    }
    *(float4*)&ndb[(size_t)grow * Nn + cb + 8 * tx] =
        make_float4(acc[i][0], acc[i][1], acc[i][2], acc[i][3]);
    *(float4*)&ndb[(size_t)grow * Nn + cb + 8 * tx + 4] =
        make_float4(acc[i][4], acc[i][5], acc[i][6], acc[i][7]);
  }
  if (!diag) {
    int lr = tid >> 3, q8 = tid & 7;
    #pragma unroll
    for (int h = 0; h < 4; ++h) {
      __syncthreads();
      if ((tx >> 2) == h) {
        int txl = tx & 3;
        if ((txl & 1) == 0) {
          #pragma unroll
          for (int j = 0; j < 8; ++j) {
            float* base = &Sc[(8 * txl + j) * 132 + 8 * ty];
            *(float4*)(base)     = make_float4(acc[0][j], acc[1][j], acc[2][j], acc[3][j]);
            *(float4*)(base + 4) = make_float4(acc[4][j], acc[5][j], acc[6][j], acc[7][j]);
          }
        } else {
          #pragma unroll
          for (int j = 0; j < 8; ++j) {
            float* base = &Sc[(8 * txl + j) * 132 + 8 * ty];
            *(float4*)(base)     = make_float4(acc[4][j], acc[5][j], acc[6][j], acc[7][j]);
            *(float4*)(base + 4) = make_float4(acc[0][j], acc[1][j], acc[2][j], acc[3][j]);
          }
        }
      }
      __syncthreads();
      int grow = cb + 32 * h + lr;
      int sw = ((lr >> 3) & 1) ? 4 : 0;     // source-row parity un-swap
      #pragma unroll
      for (int u = 0; u < 4; ++u) {
        int L = 4 * (q8 + 8 * u);
        float4 v = *(const float4*)&Sc[lr * 132 + (L ^ sw)];
        *(float4*)&ndb[(size_t)grow * Nn + rb + L] = v;
      }
    }
  }
}

// ------------------------------------------------- wave0 suffix-scan digit find
__device__ __forceinline__ void find_digit64(const int* hist, int tid,
                                             int* s_digit, int* s_kneed) {
  if (tid < 64) {
    int kneed = *s_kneed;
    int l = tid;
    int h0 = hist[4 * l], h1 = hist[4 * l + 1], h2 = hist[4 * l + 2], h3 = hist[4 * l + 3];
    int s3 = h3, s2 = h2 + s3, s1 = h1 + s2, s0 = h0 + s1;
    int cum = s0;
    #pragma unroll
    for (int off = 1; off < 64; off <<= 1) {
      int v = __shfl_down(cum, off, 64);
      if (l + off < 64) cum += v;
    }
    int ab = cum - s0;
    int suf0 = ab + s0, suf1 = ab + s1, suf2 = ab + s2, suf3 = ab + s3, suf4 = ab;
    if (suf0 >= kneed && suf1 < kneed) { *s_digit = 4 * l;     *s_kneed = kneed - suf1; }
    if (suf1 >= kneed && suf2 < kneed) { *s_digit = 4 * l + 1; *s_kneed = kneed - suf2; }
    if (suf2 >= kneed && suf3 < kneed) { *s_digit = 4 * l + 2; *s_kneed = kneed - suf3; }
    if (suf3 >= kneed && suf4 < kneed) { *s_digit = 4 * l + 3; *s_kneed = kneed - suf4; }
  }
}

// ------------------------------------------------- top-20: radix select per row
__global__ __launch_bounds__(256) void topk_k(const float* __restrict__ nd,
                                              int* __restrict__ outidx) {
  __shared__ unsigned keys[Nn];
  __shared__ unsigned ck[Nn];
  __shared__ short cidx[Nn];
  __shared__ int hist[256];
  __shared__ int s_digit, s_kneed, s_cnt, s_ncand;
  int tid = threadIdx.x;
  const float* row = nd + (size_t)blockIdx.x * Nn;
  int* orow = outidx + (size_t)blockIdx.x * KNB;
  if (tid == 0) { s_kneed = KNB; s_cnt = 0; s_ncand = 0; }
  hist[tid] = 0;
  __syncthreads();
  #pragma unroll
  for (int t = 0; t < Nn / 256; ++t) {
    int i = tid + 256 * t;
    unsigned u = __float_as_uint(row[i]);
    unsigned k = (u & 0x80000000u) ? ~u : (u | 0x80000000u);
    keys[i] = k;
    atomicAdd(&hist[k >> 24], 1);
  }
  __syncthreads();
  find_digit64(hist, tid, &s_digit, &s_kneed);
  __syncthreads();
  unsigned dig1 = (unsigned)s_digit;
  unsigned prefix = dig1 << 24;
  #pragma unroll
  for (int t = 0; t < Nn / 256; ++t) {
    int i = tid + 256 * t;
    unsigned k = keys[i];
    unsigned bb = k >> 24;
    if (bb > dig1) { int p = atomicAdd(&s_cnt, 1); orow[p] = i; }
    else if (bb == dig1) { int p = atomicAdd(&s_ncand, 1); ck[p] = k; cidx[p] = (short)i; }
  }
  __syncthreads();
  int nc = s_ncand;
  for (int shift = 16; shift >= 0; shift -= 8) {
    unsigned pm = 0xFFFFFFFFu << (shift + 8);
    hist[tid] = 0;
    __syncthreads();
    for (int j = tid; j < nc; j += 256) {
      unsigned k = ck[j];
      if (((k ^ prefix) & pm) == 0) atomicAdd(&hist[(k >> shift) & 255], 1);
    }
    __syncthreads();
    find_digit64(hist, tid, &s_digit, &s_kneed);
    __syncthreads();
    prefix |= ((unsigned)s_digit) << shift;
  }
  unsigned T = prefix;
  for (int j = tid; j < nc; j += 256)
    if (ck[j] > T) { int p = atomicAdd(&s_cnt, 1); orow[p] = (int)cidx[j]; }
  int kF = s_kneed, base = KNB - kF, last = -1;
  for (int r = 0; r < kF; ++r) {
    int loc = 0x7fffffff;
    for (int j = tid; j < nc; j += 256)
      if (ck[j] == T && (int)cidx[j] > last) loc = min(loc, (int)cidx[j]);
    hist[tid] = loc;
    __syncthreads();
    for (int s = 128; s > 0; s >>= 1) {
      if (tid < s) hist[tid] = min(hist[tid], hist[tid + s]);
      __syncthreads();
    }
    last = hist[0];
    if (tid == 0) orow[base + r] = last;
    __syncthreads();
  }
}

// ------------------------------------------------- fused GEMM: A = X*W1^T + b, Bv = X*W2^T
__global__ __launch_bounds__(256) void gemmAB_k(const float* __restrict__ X,
                                                const float* __restrict__ W,
                                                const float* __restrict__ bias,
                                                float* __restrict__ A,
                                                float* __restrict__ Bv,
                                                int COUT, int CIN) {
  __shared__ float Xs[16][132];
  __shared__ float Ws[16][132];
  int tid = threadIdx.x, tx = tid & 15, ty = tid >> 4;
  int mb = blockIdx.y * 128, cb = blockIdx.x * 128;
  int kk0 = tid & 15, rr = tid >> 4;
  int ldw = 2 * CIN;
  float acc[8][8] = {};
  for (int k0 = 0; k0 < CIN; k0 += 16) {
    int k = k0 + kk0;
    bool ok = k < CIN;
    #pragma unroll
    for (int r2 = rr; r2 < 128; r2 += 16) {
      Xs[kk0][permc(r2)] = ok ? X[(size_t)(mb + r2) * CIN + k] : 0.f;
      int c2 = cb + r2;
      const float* wr = (c2 < COUT) ? (W + (size_t)c2 * ldw)
                                    : (W + (size_t)(c2 - COUT) * ldw + CIN);
      Ws[kk0][permc(r2)] = ok ? wr[k] : 0.f;
    }
    __syncthreads();
    #pragma unroll
    for (int kk = 0; kk < 16; ++kk) {
      float4 a0 = *(const float4*)&Xs[kk][permc(8 * ty)];
      float4 a1 = *(const float4*)&Xs[kk][permc(8 * ty + 4)];
      float4 b0 = *(const float4*)&Ws[kk][permc(8 * tx)];
      float4 b1 = *(const float4*)&Ws[kk][permc(8 * tx + 4)];
      float av[8] = {a0.x, a0.y, a0.z, a0.w, a1.x, a1.y, a1.z, a1.w};
      float bv[8] = {b0.x, b0.y, b0.z, b0.w, b1.x, b1.y, b1.z, b1.w};
      #pragma unroll
      for (int i = 0; i < 8; ++i)
        #pragma unroll
        for (int j = 0; j < 8; ++j) acc[i][j] += av[i] * bv[j];
    }
    __syncthreads();
  }
  int c0 = cb + 8 * tx;
  bool isA = (c0 < COUT);
  float bb[8] = {0, 0, 0, 0, 0, 0, 0, 0};
  if (isA) {
    float4 b4a = *(const float4*)&bias[c0];
    float4 b4b = *(const float4*)&bias[c0 + 4];
    bb[0] = b4a.x; bb[1] = b4a.y; bb[2] = b4a.z; bb[3] = b4a.w;
    bb[4] = b4b.x; bb[5] = b4b.y; bb[6] = b4b.z; bb[7] = b4b.w;
  }
  float* dst = isA ? A : Bv;
  int cc = isA ? c0 : (c0 - COUT);
  #pragma unroll
  for (int i = 0; i < 8; ++i) {
    int m = mb + 8 * ty + i;
    *(float4*)&dst[(size_t)m * COUT + cc] =
        make_float4(acc[i][0] + bb[0], acc[i][1] + bb[1], acc[i][2] + bb[2], acc[i][3] + bb[3]);
    *(float4*)&dst[(size_t)m * COUT + cc + 4] =
        make_float4(acc[i][4] + bb[4], acc[i][5] + bb[5], acc[i][6] + bb[6], acc[i][7] + bb[7]);
  }
}

// ------------------------------------------------- gather-combine + stats
// XCD-aware: batch = blockIdx.x % 8 so each XCD's L2 caches one batch's Bv slice.
template <int COUT>
__global__ __launch_bounds__(256) void combine_k(const float* __restrict__ A,
                                                 const float* __restrict__ Bv,
                                                 const int* __restrict__ idx,
                                                 float* __restrict__ maxh,
                                                 float* __restrict__ minh,
                                                 float* __restrict__ gsum,
                                                 float* __restrict__ gsumsq) {
  constexpr int TPP = COUT / 4;
  constexpr int P = 256 / TPP;
  constexpr int PTS = 16;
  __shared__ float red[8][256];
  int tid = threadIdx.x;
  int p = tid / TPP, cq = tid % TPP;
  int b = blockIdx.x & 7, chunk = blockIdx.x >> 3;
  int nbase = b * Nn + chunk * PTS;
  const float4* A4 = (const float4*)A;
  const float4* B4 = (const float4*)Bv;
  float4 ts = make_float4(0, 0, 0, 0), ts2 = make_float4(0, 0, 0, 0);
  for (int it = 0; it < PTS / P; ++it) {
    int n = nbase + it * P + p;
    float4 a  = A4[(size_t)n * TPP + cq];
    float4 bc = B4[(size_t)n * TPP + cq];
    float4 base = make_float4(a.x - bc.x, a.y - bc.y, a.z - bc.z, a.w - bc.w);
    float4 mx = make_float4(-INFINITY, -INFINITY, -INFINITY, -INFINITY);
    float4 mn = make_float4(INFINITY, INFINITY, INFINITY, INFINITY);
    int gb = b * Nn;
    const int* ip = idx + (size_t)n * KNB;
    for (int k = 0; k < KNB; ++k) {
      int m = ip[k];
      float4 bn = B4[(size_t)(gb + m) * TPP + cq];
      float4 h = make_float4(base.x + bn.x, base.y + bn.y, base.z + bn.z, base.w + bn.w);
      mx.x = fmaxf(mx.x, h.x); mx.y = fmaxf(mx.y, h.y);
      mx.z = fmaxf(mx.z, h.z); mx.w = fmaxf(mx.w, h.w);
      mn.x = fminf(mn.x, h.x); mn.y = fminf(mn.y, h.y);
      mn.z = fminf(mn.z, h.z); mn.w = fminf(mn.w, h.w);
      ts.x += h.x; ts.y += h.y; ts.z += h.z; ts.w += h.w;
      ts2.x += h.x * h.x; ts2.y += h.y * h.y; ts2.z += h.z * h.z; ts2.w += h.w * h.w;
    }
    ((float4*)maxh)[(size_t)n * TPP + cq] = mx;
    ((float4*)minh)[(size_t)n * TPP + cq] = mn;
  }
  red[0][tid] = ts.x;  red[1][tid] = ts.y;  red[2][tid] = ts.z;  red[3][tid] = ts.w;
  red[4][tid] = ts2.x; red[5][tid] = ts2.y; red[6][tid] = ts2.z; red[7][tid] = ts2.w;
  __syncthreads();
  if (tid < COUT) {
    int q = tid & 3, g = tid >> 2;
    float s = 0.f, s2 = 0.f;
    for (int pp = 0; pp < P; ++pp) {
      int t2 = pp * TPP + g;
      s += red[q][t2]; s2 += red[4 + q][t2];
    }
    atomicAdd(&gsum[tid], s);
    atomicAdd(&gsumsq[tid], s2);
  }
}

// ------------------------------------------------- BN scale/shift per channel
__global__ void stats_k(const float* __restrict__ gsum, const float* __restrict__ gsumsq,
                        const float* __restrict__ gamma, const float* __restrict__ beta,
                        float* __restrict__ sA, float* __restrict__ sB, int COUT) {
  int c = threadIdx.x;
  if (c < COUT) {
    const float cnt = (float)((size_t)Bb * Nn * KNB);
    float mean = gsum[c] / cnt;
    float var = gsumsq[c] / cnt - mean * mean;
    var = fmaxf(var, 0.f);
    float s = gamma[c] * rsqrtf(var + EPSBN);
    sA[c] = s;
    sB[c] = beta[c] - mean * s;
  }
}

// ------------------------------------------------- apply BN+ReLU (layers 1,2)
__global__ __launch_bounds__(256) void apply_k(const float* __restrict__ maxh,
                                               const float* __restrict__ minh,
                                               const float* __restrict__ sA,
                                               const float* __restrict__ sB,
                                               float* __restrict__ out, int COUT) {
  int i = blockIdx.x * 256 + threadIdx.x;
  if (i >= NPT * COUT) return;
  int c = i % COUT;
  float s = sA[c];
  float h = (s >= 0.f) ? maxh[i] : minh[i];
  out[i] = fmaxf(s * h + sB[c], 0.f);
}

// ------------------------------------------------- layer-3 fused BN+ReLU+pool
__global__ __launch_bounds__(256) void gmax3_k(const float* __restrict__ maxh,
                                               const float* __restrict__ minh,
                                               const float* __restrict__ sA,
                                               const float* __restrict__ sB,
                                               unsigned* __restrict__ pooled) {
  int b = blockIdx.y, chunk = blockIdx.x;
  int c = threadIdx.x;
  float s = sA[c], t = sB[c];
  const float* src = (s >= 0.f) ? maxh : minh;
  const float* fb = src + ((size_t)b * Nn + chunk * 32) * 256;
  float m = 0.f;
  #pragma unroll 8
  for (int r = 0; r < 32; ++r) m = fmaxf(m, fmaxf(s * fb[(size_t)r * 256 + c] + t, 0.f));
  atomicMax(&pooled[b * 256 + c], __float_as_uint(m));
}

// ------------------------------------------------- final linear 8x256 @ 256x256
__global__ void final_k(const float* __restrict__ pooled, const float* __restrict__ wo,
                        const float* __restrict__ bo, float* __restrict__ out) {
  int b = blockIdx.x, c = threadIdx.x;
  const float* pr = pooled + b * 256;
  const float* wr = wo + c * 256;
  float s = bo[c];
  for (int j = 0; j < 256; ++j) s += pr[j] * wr[j];
  out[b * 256 + c] = s;
}

// ------------------------------------------------- layer driver
template <int CIN, int COUT, bool LAST>
static void run_layer(const float* fin, const float* W, const float* bias,
                      const float* gamma, const float* beta, float* fout,
                      float* nd, bool big, float* Abuf, float* Bvbuf, int* idxb,
                      float* xx, float* maxh, float* minh, float* gsum,
                      float* sA, float* sB, unsigned* pooled, hipStream_t stream) {
  row_sumsq_k<<<(NPT + 255) / 256, 256, 0, stream>>>(fin, xx, CIN);
  if (big) {
    dist_k<<<dim3(136 * Bb), 256, 0, stream>>>(fin, xx, nd, CIN);
    topk_k<<<NPT, 256, 0, stream>>>(nd, idxb);
  } else {
    for (int b = 0; b < Bb; ++b) {
      dist_k<<<dim3(136, 1, 1), 256, 0, stream>>>(
          fin + (size_t)b * Nn * CIN, xx + (size_t)b * Nn, nd, CIN);
      topk_k<<<Nn, 256, 0, stream>>>(nd, idxb + (size_t)b * Nn * KNB);
    }
  }
  gemmAB_k<<<dim3(2 * COUT / 128, NPT / 128), 256, 0, stream>>>(fin, W, bias,
                                                                Abuf, Bvbuf, COUT, CIN);
  hipMemsetAsync(gsum, 0, 2 * 256 * sizeof(float), stream);
  combine_k<COUT><<<NPT / 16, 256, 0, stream>>>(Abuf, Bvbuf, idxb, maxh, minh,
                                                gsum, gsum + 256);
  stats_k<<<1, 256, 0, stream>>>(gsum, gsum + 256, gamma, beta, sA, sB, COUT);
  if (LAST) {
    gmax3_k<<<dim3(Nn / 32, Bb), 256, 0, stream>>>(maxh, minh, sA, sB, pooled);
  } else {
    apply_k<<<(NPT * COUT + 255) / 256, 256, 0, stream>>>(maxh, minh, sA, sB, fout, COUT);
  }
}

extern "C" void kernel_launch(void* const* d_in, const int* in_sizes, int n_in,
                              void* d_out, int out_size, void* d_ws, size_t ws_size,
                              hipStream_t stream) {
  const float* x   = (const float*)d_in[0];
  const float* w1  = (const float*)d_in[1];
  const float* b1  = (const float*)d_in[2];
  const float* g1  = (const float*)d_in[3];
  const float* be1 = (const float*)d_in[4];
  const float* w2  = (const float*)d_in[5];
  const float* b2  = (const float*)d_in[6];
  const float* g2  = (const float*)d_in[7];
  const float* be2 = (const float*)d_in[8];
  const float* w3  = (const float*)d_in[9];
  const float* b3  = (const float*)d_in[10];
  const float* g3  = (const float*)d_in[11];
  const float* be3 = (const float*)d_in[12];
  const float* wo  = (const float*)d_in[13];
  const float* bo  = (const float*)d_in[14];
  float* out = (float*)d_out;

  char* ws = (char*)d_ws;
  size_t off = 0;
  auto grab = [&](size_t bytes) -> char* {
    char* p = ws + off;
    off = (off + bytes + 255) & ~(size_t)255;
    return p;
  };
  const size_t SLAB = (size_t)NPT * 256 * 4;          // 16.78 MB
  const size_t ND_ALL = (size_t)Bb * Nn * Nn * 4;     // 134.2 MB
  const size_t NEED_BIG = ND_ALL + ((size_t)NPT * KNB * 4) + ((size_t)NPT * 4) +
                          ((size_t)NPT * 64 * 4) + ((size_t)NPT * 128 * 4) +
                          (16 << 10) + 16 * 256;
  bool big = (ws_size >= NEED_BIG);

  float *nd, *Abuf, *Bvbuf, *maxh, *minh;
  if (big) {
    nd    = (float*)grab(ND_ALL);
    Abuf  = nd;
    Bvbuf = (float*)((char*)nd + SLAB);
    maxh  = (float*)((char*)nd + 2 * SLAB);
    minh  = (float*)((char*)nd + 3 * SLAB);
  } else {
    nd    = (float*)grab((size_t)Nn * Nn * 4);
    Abuf  = nd;
    Bvbuf = (float*)grab(SLAB);
    maxh  = nullptr; minh = nullptr;
  }
  int*   idxb  = (int*)  grab((size_t)NPT * KNB * 4);
  float* xx    = (float*)grab((size_t)NPT * 4);
  float* feat1 = (float*)grab((size_t)NPT * 64 * 4);
  float* feat2 = (float*)grab((size_t)NPT * 128 * 4);
  if (!big) {
    maxh = (float*)grab(SLAB);
    minh = (float*)grab(SLAB);
  }
  float* gsum  = (float*)grab(2 * 256 * 4);
  float* sA    = (float*)grab(256 * 4);
  float* sB    = (float*)grab(256 * 4);
  unsigned* pooled = (unsigned*)grab(Bb * 256 * 4);

  hipMemsetAsync(pooled, 0, Bb * 256 * sizeof(unsigned), stream);

  run_layer<3, 64, false>(x, w1, b1, g1, be1, feat1, nd, big, Abuf, Bvbuf, idxb, xx,
                          maxh, minh, gsum, sA, sB, pooled, stream);
  run_layer<64, 128, false>(feat1, w2, b2, g2, be2, feat2, nd, big, Abuf, Bvbuf, idxb, xx,
                            maxh, minh, gsum, sA, sB, pooled, stream);
  run_layer<128, 256, true>(feat2, w3, b3, g3, be3, nullptr, nd, big, Abuf, Bvbuf, idxb, xx,
                            maxh, minh, gsum, sA, sB, pooled, stream);

  final_k<<<Bb, 256, 0, stream>>>((const float*)pooled, wo, bo, out);
  (void)in_sizes; (void)n_in; (void)out_size;
}